// Round 2
// baseline (532.927 us; speedup 1.0000x reference)
//
#include <hip/hip_runtime.h>
#include <stdint.h>

// WindowedAttn on MI355X (gfx950) — round 2
// GEMMs: 128x256 block tile (wave tile 64x128, 4x8 acc) to cut LDS-read bytes
//   per FLOP from 32 -> 43.7 FLOP/B (R1 was ds_read-bound: 16KB LDS per 32 MFMA).
//   XOR-swizzled LDS (chunk ^ (row&7)) kept: R1 measured SQ_LDS_BANK_CONFLICT=0.
// Attention: double-buffered Vt/Ps -> ONE barrier per 64-K step; V global loads
//   hoisted above the S=K*Q^T MFMA phase; exp2-domain softmax; v_perm bf16 pack.

typedef unsigned short u16;
typedef unsigned int u32;
typedef __attribute__((ext_vector_type(8))) short bf16x8;   // 8 bf16 = 4 VGPRs
typedef __attribute__((ext_vector_type(4))) float f32x4;

#define QKVN 6144
#define DM 2048

__device__ __forceinline__ u16 f2b(float f) {
  u32 u = __builtin_bit_cast(u32, f);
  u32 r = (u + 0x7fffu + ((u >> 16) & 1u)) >> 16;  // RNE
  return (u16)r;
}

// one v_perm_b32: {hi.high16, lo.high16} (bf16 truncation pack)
__device__ __forceinline__ u32 pack_hi16(float hi, float lo) {
  return __builtin_amdgcn_perm(__builtin_bit_cast(u32, hi),
                               __builtin_bit_cast(u32, lo), 0x07060302u);
}

__device__ __forceinline__ float fexp2(float x) { return __builtin_amdgcn_exp2f(x); }

__device__ __forceinline__ void gload_lds16(const void* g, void* l) {
  __builtin_amdgcn_global_load_lds((const __attribute__((address_space(1))) void*)g,
                                   (__attribute__((address_space(3))) void*)l,
                                   16, 0, 0);
}

// ---------------- prep kernels ----------------

__global__ void cast_f32_bf16(const float4* __restrict__ x, uint4* __restrict__ o) {
  int idx = blockIdx.x * 256 + threadIdx.x;
  float4 a = x[2 * idx];
  float4 b = x[2 * idx + 1];
  uint4 r;
  r.x = (u32)f2b(a.x) | ((u32)f2b(a.y) << 16);
  r.y = (u32)f2b(a.z) | ((u32)f2b(a.w) << 16);
  r.z = (u32)f2b(b.x) | ((u32)f2b(b.y) << 16);
  r.w = (u32)f2b(b.z) | ((u32)f2b(b.w) << 16);
  o[idx] = r;
}

// W (K x N, fp32, row-major) -> Wt (N x K, bf16, row-major)
__global__ void transpose_cast(const float* __restrict__ W, u16* __restrict__ Wt,
                               int K, int N) {
  __shared__ u16 tile[64][65];
  int tx = threadIdx.x & 63;
  int ty = threadIdx.x >> 6;
  int n0 = blockIdx.x * 64;
  int k0 = blockIdx.y * 64;
#pragma unroll
  for (int r = 0; r < 64; r += 4)
    tile[r + ty][tx] = f2b(W[(size_t)(k0 + r + ty) * N + n0 + tx]);
  __syncthreads();
#pragma unroll
  for (int r = 0; r < 64; r += 4)
    Wt[(size_t)(n0 + r + ty) * K + k0 + tx] = tile[tx][r + ty];
}

// ---------------- GEMM: C[M][N] = A[M][K] * Bt[N][K]^T + bias ----------------
// block 256 = 4 waves (2x2 of 64x128), 4x8 16x16x32 mfma per wave, BK=64

template <typename TO>
__global__ __launch_bounds__(256, 2) void gemm_bt(const u16* __restrict__ A,
                                                  const u16* __restrict__ Bt,
                                                  const float* __restrict__ bias,
                                                  TO* __restrict__ C,
                                                  int M, int N, int K) {
  __shared__ u16 As[128 * 64];   // 16 KB
  __shared__ u16 Bs[256 * 64];   // 32 KB
  const int tid = threadIdx.x;
  const int lane = tid & 63;
  const int wave = tid >> 6;
  const int quad = lane >> 4;
  const int l15 = lane & 15;
  const int m0 = blockIdx.y * 128;
  const int n0 = blockIdx.x * 256;
  const int wm = (wave & 1) * 64;
  const int wn = (wave >> 1) * 128;

  f32x4 acc[4][8] = {};

  for (int k0 = 0; k0 < K; k0 += 64) {
    // stage A (128 rows) + B (256 rows); row = 8 chunks of 16B, stored c' = c ^ (row&7)
#pragma unroll
    for (int i = 0; i < 4; ++i) {
      int sb = wave * 256 + i * 64;
      int s = sb + lane;
      int m = s >> 3;
      int c = (s & 7) ^ (m & 7);
      gload_lds16(A + (size_t)(m0 + m) * K + (k0 + c * 8), As + sb * 8);
    }
#pragma unroll
    for (int i = 0; i < 8; ++i) {
      int sb = wave * 512 + i * 64;
      int s = sb + lane;
      int n = s >> 3;
      int c = (s & 7) ^ (n & 7);
      gload_lds16(Bt + (size_t)(n0 + n) * K + (k0 + c * 8), Bs + sb * 8);
    }
    __syncthreads();
#pragma unroll
    for (int ks = 0; ks < 2; ++ks) {
      bf16x8 af[4], bf[8];
#pragma unroll
      for (int i = 0; i < 4; ++i) {
        int m = wm + i * 16 + l15;
        af[i] = *(const bf16x8*)(As + m * 64 + (((ks * 4 + quad) ^ (m & 7)) << 3));
      }
#pragma unroll
      for (int j = 0; j < 8; ++j) {
        int n = wn + j * 16 + l15;
        bf[j] = *(const bf16x8*)(Bs + n * 64 + (((ks * 4 + quad) ^ (n & 7)) << 3));
      }
#pragma unroll
      for (int i = 0; i < 4; ++i)
#pragma unroll
        for (int j = 0; j < 8; ++j)
          acc[i][j] = __builtin_amdgcn_mfma_f32_16x16x32_bf16(af[i], bf[j], acc[i][j], 0, 0, 0);
    }
    __syncthreads();
  }

  // epilogue: D row=(quad*4+t), col=l15 (m89-verified)
#pragma unroll
  for (int j = 0; j < 8; ++j) {
    int col = n0 + wn + j * 16 + l15;
    float bv = bias[col];
#pragma unroll
    for (int i = 0; i < 4; ++i) {
      int row = m0 + wm + i * 16 + quad * 4;
#pragma unroll
      for (int t = 0; t < 4; ++t) {
        float v = acc[i][j][t] + bv;
        if constexpr (sizeof(TO) == 2)
          C[(size_t)(row + t) * N + col] = (TO)f2b(v);
        else
          C[(size_t)(row + t) * N + col] = (TO)v;
      }
    }
  }
}

// ---------------- attention ----------------
// One block per (b, h, win, qtile of 128). kk-tiles of 64, double-buffered LDS,
// single barrier per tile. S^T = K*Q^T ; O^T += V^T * P^T.

template <bool MASK>
__device__ __forceinline__ void attn_step(
    int jt, int tid, int wave, int quad, int l15, int qt, int tokw, int h,
    const u16* __restrict__ qkv, u16* Vt, u16* Ps,
    const bf16x8 (&qf)[2][4], f32x4 (&acc_o)[8][2], float (&mrun)[2],
    float (&lrun)[2]) {
  const float SL2E = 0.12751745f;  // SCALE * log2(e)
  u16* VtB = Vt + (jt & 1) * (128 * 64);
  u16* PsB = Ps + (jt & 1) * (128 * 64);

  // ---- issue V loads early (latency hides under S-phase MFMA) ----
  const u16* Vb = qkv + (size_t)(tokw + jt * 64) * QKVN + 4096 + h * 128;
  const int p = tid & 31;
  const int dc0 = tid >> 5;          // d-chunk 0..7 (+8 for second half)
  const int kk0 = p * 2;
  const u16* g0 = Vb + (size_t)kk0 * QKVN + dc0 * 8;
  uint4 vr0 = *(const uint4*)g0;
  uint4 vr1 = *(const uint4*)(g0 + QKVN);
  uint4 vr2 = *(const uint4*)(g0 + 64);
  uint4 vr3 = *(const uint4*)(g0 + QKVN + 64);

  // ---- S^T = K * Q^T ----
  f32x4 acc_s[4][2] = {};
  {
    const u16* Kb = qkv + (size_t)(tokw + jt * 64) * QKVN + 2048 + h * 128;
    bf16x8 kf[4][4];
#pragma unroll
    for (int i = 0; i < 4; ++i) {
      const u16* Kr = Kb + (size_t)(i * 16 + l15) * QKVN + quad * 8;
#pragma unroll
      for (int ks = 0; ks < 4; ++ks)
        kf[i][ks] = *(const bf16x8*)(Kr + ks * 32);
    }
#pragma unroll
    for (int ks = 0; ks < 4; ++ks)
#pragma unroll
      for (int i = 0; i < 4; ++i)
#pragma unroll
        for (int j = 0; j < 2; ++j)
          acc_s[i][j] = __builtin_amdgcn_mfma_f32_16x16x32_bf16(kf[i][ks], qf[j][ks],
                                                                acc_s[i][j], 0, 0, 0);
  }

  // ---- write V^T tile to LDS (transpose, pairwise packed, XOR-swizzled) ----
  {
    const u16* a0 = (const u16*)&vr0;
    const u16* a1 = (const u16*)&vr1;
    const u16* a2 = (const u16*)&vr2;
    const u16* a3 = (const u16*)&vr3;
    int c = kk0 >> 3;
    int boff = (kk0 & 7) << 1;
#pragma unroll
    for (int j = 0; j < 8; ++j) {
      int d = dc0 * 8 + j;
      *(u32*)((char*)VtB + d * 128 + ((c ^ (d & 7)) << 4) + boff) =
          (u32)a0[j] | ((u32)a1[j] << 16);
      int d2 = d + 64;
      *(u32*)((char*)VtB + d2 * 128 + ((c ^ (d2 & 7)) << 4) + boff) =
          (u32)a2[j] | ((u32)a3[j] << 16);
    }
  }

  // ---- online softmax (exp2 domain; per-lane q state) ----
#pragma unroll
  for (int j = 0; j < 2; ++j) {
    int ql = wave * 32 + j * 16 + l15;
    float vmax = -1e30f;
#pragma unroll
    for (int i = 0; i < 4; ++i)
#pragma unroll
      for (int t = 0; t < 4; ++t) {
        float s = acc_s[i][j][t];
        if (MASK) {
          int kg = jt * 64 + i * 16 + quad * 4 + t;
          if (kg > qt * 128 + ql) s = -1e30f;
          acc_s[i][j][t] = s;
        }
        vmax = fmaxf(vmax, s);
      }
    vmax = fmaxf(vmax, __shfl_xor(vmax, 16));
    vmax = fmaxf(vmax, __shfl_xor(vmax, 32));
    float mnew = fmaxf(mrun[j], vmax * SL2E);
    float alpha = fexp2(mrun[j] - mnew);
    mrun[j] = mnew;
    float vsum = 0.f;
#pragma unroll
    for (int i = 0; i < 4; ++i) {
      float p0 = fexp2(__builtin_fmaf(acc_s[i][j][0], SL2E, -mnew));
      float p1 = fexp2(__builtin_fmaf(acc_s[i][j][1], SL2E, -mnew));
      float p2 = fexp2(__builtin_fmaf(acc_s[i][j][2], SL2E, -mnew));
      float p3 = fexp2(__builtin_fmaf(acc_s[i][j][3], SL2E, -mnew));
      vsum += (p0 + p1) + (p2 + p3);
      uint2 pk;
      pk.x = pack_hi16(p1, p0);
      pk.y = pack_hi16(p3, p2);
      int kk = i * 16 + quad * 4;
      *(uint2*)((char*)PsB + ql * 128 + (((kk >> 3) ^ (ql & 7)) << 4) + ((kk & 7) << 1)) = pk;
    }
    vsum += __shfl_xor(vsum, 16);
    vsum += __shfl_xor(vsum, 32);
    lrun[j] = lrun[j] * alpha + vsum;
    if (__ballot(alpha < 0.99995f)) {  // wave-uniform skip when no lane rescales
#pragma unroll
      for (int i2 = 0; i2 < 8; ++i2)
#pragma unroll
        for (int t = 0; t < 4; ++t)
          acc_o[i2][j][t] *= alpha;
    }
  }
  __syncthreads();  // Vt/Ps(buf) visible; also fences prev-prev buf reuse

  // ---- O^T += V^T * P^T ----
#pragma unroll
  for (int ks = 0; ks < 2; ++ks) {
    int kc = ks * 4 + quad;
    bf16x8 pf[2];
#pragma unroll
    for (int j = 0; j < 2; ++j) {
      int ql = wave * 32 + j * 16 + l15;
      pf[j] = *(const bf16x8*)((char*)PsB + ql * 128 + ((kc ^ (ql & 7)) << 4));
    }
#pragma unroll
    for (int i2 = 0; i2 < 8; ++i2) {
      int d = i2 * 16 + l15;
      bf16x8 vf = *(const bf16x8*)((char*)VtB + d * 128 + ((kc ^ (d & 7)) << 4));
#pragma unroll
      for (int j = 0; j < 2; ++j)
        acc_o[i2][j] = __builtin_amdgcn_mfma_f32_16x16x32_bf16(vf, pf[j], acc_o[i2][j], 0, 0, 0);
    }
  }
}

__global__ __launch_bounds__(256, 2) void attn_win(const u16* __restrict__ qkv,
                                                   u16* __restrict__ attn_out) {
  __shared__ u16 Vt[2 * 128 * 64];  // [buf][d][kk], chunk ^ (d&7)   32 KB
  __shared__ u16 Ps[2 * 128 * 64];  // [buf][q][kk], chunk ^ (q&7)   32 KB
  const int tid = threadIdx.x;
  const int lane = tid & 63;
  const int wave = tid >> 6;
  const int quad = lane >> 4;
  const int l15 = lane & 15;
  const int qt = blockIdx.x;
  const int win = blockIdx.y;
  const int b = blockIdx.z >> 4;
  const int h = blockIdx.z & 15;
  const int tokw = b * 4096 + win * 512;
  const int tokq = tokw + qt * 128;

  bf16x8 qf[2][4];
  {
    const u16* Qb = qkv + (size_t)tokq * QKVN + h * 128;
#pragma unroll
    for (int j = 0; j < 2; ++j) {
      const u16* Qr = Qb + (size_t)(wave * 32 + j * 16 + l15) * QKVN + quad * 8;
#pragma unroll
      for (int ks = 0; ks < 4; ++ks)
        qf[j][ks] = *(const bf16x8*)(Qr + ks * 32);
    }
  }

  f32x4 acc_o[8][2] = {};
  float mrun[2] = {-1e30f, -1e30f};
  float lrun[2] = {0.f, 0.f};

  int jt = 0;
  const int diag = 2 * qt;
  for (; jt < diag; ++jt)
    attn_step<false>(jt, tid, wave, quad, l15, qt, tokw, h, qkv, Vt, Ps, qf, acc_o, mrun, lrun);
  for (; jt <= diag + 1; ++jt)
    attn_step<true>(jt, tid, wave, quad, l15, qt, tokw, h, qkv, Vt, Ps, qf, acc_o, mrun, lrun);

  // ---- epilogue: O^T C-layout -> attn_out[tok][h*128+d] (RNE kept here) ----
#pragma unroll
  for (int j = 0; j < 2; ++j) {
    float inv = 1.0f / lrun[j];
    int ql = wave * 32 + j * 16 + l15;
    u16* orow = attn_out + (size_t)(tokq + ql) * DM + h * 128;
#pragma unroll
    for (int i2 = 0; i2 < 8; ++i2) {
      int d = i2 * 16 + quad * 4;
      uint2 pk;
      pk.x = (u32)f2b(acc_o[i2][j][0] * inv) | ((u32)f2b(acc_o[i2][j][1] * inv) << 16);
      pk.y = (u32)f2b(acc_o[i2][j][2] * inv) | ((u32)f2b(acc_o[i2][j][3] * inv) << 16);
      *(uint2*)(orow + d) = pk;
    }
  }
}

// ---------------- launch ----------------

extern "C" void kernel_launch(void* const* d_in, const int* in_sizes, int n_in,
                              void* d_out, int out_size, void* d_ws, size_t ws_size,
                              hipStream_t stream) {
  const float* x = (const float*)d_in[0];
  const float* W_qkv = (const float*)d_in[1];
  const float* b_qkv = (const float*)d_in[2];
  const float* W_out = (const float*)d_in[3];
  const float* b_out = (const float*)d_in[4];
  float* out = (float*)d_out;

  char* w = (char*)d_ws;
  u16* xb = (u16*)w;                                   // 32MB [8192][2048]; reused as attn_out
  u16* wqkvT = (u16*)(w + 33554432);                   // 24MB [6144][2048]
  u16* woutT = (u16*)(w + 33554432 + 25165824);        // 8MB  [2048][2048]
  u16* qkv = (u16*)(w + 67108864);                     // 96MB [8192][6144]

  cast_f32_bf16<<<8192, 256, 0, stream>>>((const float4*)x, (uint4*)xb);
  transpose_cast<<<dim3(96, 32), 256, 0, stream>>>(W_qkv, wqkvT, 2048, 6144);
  transpose_cast<<<dim3(32, 32), 256, 0, stream>>>(W_out, woutT, 2048, 2048);
  gemm_bt<u16><<<dim3(24, 64), 256, 0, stream>>>(xb, wqkvT, b_qkv, qkv, 8192, 6144, 2048);
  attn_win<<<dim3(4, 8, 32), 256, 0, stream>>>(qkv, xb);
  gemm_bt<float><<<dim3(8, 64), 256, 0, stream>>>(xb, woutT, b_out, out, 8192, 2048, 2048);
}